// Round 10
// baseline (193.396 us; speedup 1.0000x reference)
//
#include <hip/hip_runtime.h>
#include <hip/hip_bf16.h>
#include <math.h>

// ---------------- problem constants ----------------
#define SS 16
#define NSTEP 91
#define NA 128
#define NPL 2048
#define NPLN 20
#define NTLS 64
#define SC 10          // STEP_CURRENT
#define NH 11          // N_HIST
#define NF 80          // N_FUT
#define NT 16          // N_TARGET
#define NO 64          // N_OTHER
#define NM 512         // N_MAP
#define NTL 40         // N_TL

// ---------------- output offsets (floats) ----------------
#define OFF_REF_POS   0
#define OFF_REF_ROT   512
#define OFF_TGT_POS   1536
#define OFF_TGT_VEL   7168
#define OFF_TGT_SPD   12800
#define OFF_TGT_ACC   15616
#define OFF_TGT_YAW   18432
#define OFF_TGT_YR    21248
#define OFF_TGT_SIZE  24064
#define OFF_GT_POS    24832
#define OFF_GT_VEL    65792
#define OFF_GT_SPD    106752
#define OFF_GT_YAW    127232
#define OFF_OTH_POS   147712
#define OFF_OTH_VEL   508160
#define OFF_OTH_SPD   868608
#define OFF_OTH_ACC   1048832
#define OFF_OTH_YAW   1229056
#define OFF_OTH_YR    1409280
#define OFF_OTH_SIZE  1589504
#define OFF_M_POS     1638656
#define OFF_M_DIR     6881536
#define OFF_TL_POS    12124416
#define OFF_TL_DIR    12349696
#define OFF_TIDX      12574976
#define OFF_REF_TYPE  12575232
#define OFF_REF_ROLE  12576000
#define OFF_TGT_VALID 12576768
#define OFF_GT_VALID  12579584
#define OFF_GT_CMD    12600064
#define OFF_OTH_VALID 12602112
#define OFF_OTH_TYPE  12782336
#define OFF_OTH_ROLE  12831488
#define OFF_M_VALID   12880640
#define OFF_M_TYPE    15502080
#define OFF_TL_VALID  16943872
#define OFF_TL_STATE  17056512
// total = 17619712

// Sort key: FLOAT64 distance (matching a numpy-f64 reference's ranking),
// bit-packed order-isomorphically with the element index in the 11 LSBs.
// Non-negative doubles: ascending bit pattern == ascending value. Masking
// the low 11 mantissa bits (~5e-11 rel resolution) cannot flip any genuine
// pair; for invalid entries the key is +inf-pattern | idx → inf entries
// order by index, exactly like np's stable tie-break.
__device__ __forceinline__ unsigned long long
dist_key(float px, float py, float rx, float ry, int idx, bool valid) {
    if (!valid) return 0x7FF0000000000000ull | (unsigned long long)(unsigned)idx;
    double dx = (double)px - (double)rx;
    double dy = (double)py - (double)ry;
    double d  = sqrt(__dadd_rn(__dmul_rn(dx, dx), __dmul_rn(dy, dy)));
    unsigned long long b = (unsigned long long)__double_as_longlong(d);
    return (b & ~2047ull) | (unsigned long long)(unsigned)idx;
}
// Reconstruct (approximately) the distance for the <2000/<3000 checks.
// Invalid keys reconstruct as NaN (0x7FF0..|idx with idx!=0) or inf → false.
__device__ __forceinline__ bool key_lt(unsigned long long kk, double thr) {
    double d = __longlong_as_double((long long)(kk & ~2047ull));
    return d < thr;
}

// =====================================================================
// K1: block-per-scene target selection (top-16 of 128 by w, stable).
// [VERIFIED PASSING — do not touch]
// =====================================================================
__global__ void k1_targets(const int* __restrict__ agent_valid,
                           const float* __restrict__ agent_pos,
                           const float* __restrict__ agent_yaw,
                           const int* __restrict__ agent_type,
                           const int* __restrict__ agent_role,
                           const float* __restrict__ agent_size,
                           const int* __restrict__ agent_cmd,
                           float* __restrict__ out,
                           int* __restrict__ tidx_ws,
                           float* __restrict__ refx_ws,
                           float* __restrict__ refy_ws,
                           float* __restrict__ refyaw_ws) {
    __shared__ int wred[2];
    int s = blockIdx.x;
    int a = threadIdx.x;            // 0..127
    int w = agent_role[(s * NA + a) * 3 + 0] +
            agent_role[(s * NA + a) * 3 + 1] +
            agent_role[(s * NA + a) * 3 + 2] +
            agent_valid[(s * NSTEP + SC) * NA + a];
    int packed = (w << 8) | (127 - a);
    for (int p = 0; p < NT; ++p) {
        int v = packed;
        for (int d = 32; d > 0; d >>= 1) v = max(v, __shfl_xor(v, d));
        if ((threadIdx.x & 63) == 0) wred[threadIdx.x >> 6] = v;
        __syncthreads();
        int m = max(wred[0], wred[1]);
        __syncthreads();
        int best = 127 - (m & 0xFF);
        if (a == best) {
            packed = -1;            // remove from future rounds
            int st = s * NT + p;
            tidx_ws[st] = a;
            out[OFF_TIDX + st] = (float)a;
            float px = agent_pos[((s * NSTEP + SC) * NA + a) * 2 + 0];
            float py = agent_pos[((s * NSTEP + SC) * NA + a) * 2 + 1];
            float yaw = agent_yaw[(s * NSTEP + SC) * NA + a];
            refx_ws[st] = px; refy_ws[st] = py; refyaw_ws[st] = yaw;
            float c = cosf(yaw), sn = sinf(yaw);
            out[OFF_REF_POS + st * 2 + 0] = px;
            out[OFF_REF_POS + st * 2 + 1] = py;
            out[OFF_REF_ROT + st * 4 + 0] = c;
            out[OFF_REF_ROT + st * 4 + 1] = -sn;
            out[OFF_REF_ROT + st * 4 + 2] = sn;
            out[OFF_REF_ROT + st * 4 + 3] = c;
            for (int k = 0; k < 3; ++k) {
                out[OFF_REF_TYPE + st * 3 + k] = (float)agent_type[(s * NA + a) * 3 + k];
                out[OFF_REF_ROLE + st * 3 + k] = (float)agent_role[(s * NA + a) * 3 + k];
                out[OFF_TGT_SIZE + st * 3 + k] = agent_size[(s * NA + a) * 3 + k];
            }
            for (int k = 0; k < 8; ++k)
                out[OFF_GT_CMD + st * 8 + k] = (float)agent_cmd[(s * NA + a) * 8 + k];
        }
    }
}

// =====================================================================
// K2: target history + future [VERIFIED PASSING — do not touch]
// =====================================================================
__global__ void k2_tgt(const int* __restrict__ agent_valid,
                       const float* __restrict__ agent_pos,
                       const float* __restrict__ agent_vel,
                       const float* __restrict__ agent_spd,
                       const float* __restrict__ agent_acc,
                       const float* __restrict__ agent_yaw,
                       const float* __restrict__ agent_yr,
                       float* __restrict__ out,
                       const int* __restrict__ tidx_ws,
                       const float* __restrict__ refx_ws,
                       const float* __restrict__ refy_ws,
                       const float* __restrict__ refyaw_ws) {
    int idx = blockIdx.x * blockDim.x + threadIdx.x;
    if (idx >= SS * NT * NSTEP) return;
    int step = idx % NSTEP;
    int t = (idx / NSTEP) % NT;
    int s = idx / (NSTEP * NT);
    int st = s * NT + t;
    int a = tidx_ws[st];
    float rx = refx_ws[st], ry = refy_ws[st], ryaw = refyaw_ws[st];
    float c = cosf(ryaw), sn = sinf(ryaw);
    int gi = (s * NSTEP + step) * NA + a;
    float2 p = *(const float2*)&agent_pos[gi * 2];
    float px = p.x - rx, py = p.y - ry;
    float2 v = *(const float2*)&agent_vel[gi * 2];
    float2 op = make_float2(px * c + py * sn, -px * sn + py * c);
    float2 ov = make_float2(v.x * c + v.y * sn, -v.x * sn + v.y * c);
    float spd = agent_spd[gi];
    float dyaw = agent_yaw[gi] - ryaw;
    float lyaw = atan2f(sinf(dyaw), cosf(dyaw));
    float vld = (float)agent_valid[gi];
    if (step < NH) {
        int hi = st * NH + step;
        *(float2*)&out[OFF_TGT_POS + hi * 2] = op;
        *(float2*)&out[OFF_TGT_VEL + hi * 2] = ov;
        out[OFF_TGT_SPD + hi] = spd;
        out[OFF_TGT_ACC + hi] = agent_acc[gi];
        out[OFF_TGT_YAW + hi] = lyaw;
        out[OFF_TGT_YR + hi] = agent_yr[gi];
        out[OFF_TGT_VALID + hi] = vld;
    } else {
        int fi = st * NF + (step - NH);
        *(float2*)&out[OFF_GT_POS + fi * 2] = op;
        *(float2*)&out[OFF_GT_VEL + fi * 2] = ov;
        out[OFF_GT_SPD + fi] = spd;
        out[OFF_GT_YAW + fi] = lyaw;
        out[OFF_GT_VALID + fi] = vld;
    }
}

// =====================================================================
// K3: others — per (s,t) block: top-64 of 128 by f64 dist (stable).
// Classic bitonic, barrier every pass. [sort/gather PASSED round 6]
// =====================================================================
__global__ void k3_others(const int* __restrict__ agent_valid,
                          const float* __restrict__ agent_pos,
                          const float* __restrict__ agent_vel,
                          const float* __restrict__ agent_spd,
                          const float* __restrict__ agent_acc,
                          const float* __restrict__ agent_yaw,
                          const float* __restrict__ agent_yr,
                          const int* __restrict__ agent_type,
                          const int* __restrict__ agent_role,
                          const float* __restrict__ agent_size,
                          float* __restrict__ out,
                          const int* __restrict__ tidx_ws,
                          const float* __restrict__ refx_ws,
                          const float* __restrict__ refy_ws,
                          const float* __restrict__ refyaw_ws) {
    __shared__ unsigned long long key[NA];
    int bid = blockIdx.x;
    int s = bid & (SS - 1), t = bid >> 4;   // scene-major for XCD/L2 grouping
    int st = s * NT + t;
    int tid = threadIdx.x;
    float rx = refx_ws[st], ry = refy_ws[st], ryaw = refyaw_ws[st];
    float c = cosf(ryaw), sn = sinf(ryaw);
    int tgt = tidx_ws[st];
    {
        int a = tid;
        int va = agent_valid[(s * NSTEP + SC) * NA + a];
        float2 p = *(const float2*)&agent_pos[((s * NSTEP + SC) * NA + a) * 2];
        key[a] = dist_key(p.x, p.y, rx, ry, a, va && (a != tgt));
    }
    for (int k = 2; k <= NA; k <<= 1)
        for (int j = k >> 1; j > 0; j >>= 1) {
            __syncthreads();
            int i = tid, ixj = i ^ j;
            if (ixj > i) {
                unsigned long long x = key[i], y = key[ixj];
                bool up = ((i & k) == 0);
                if (up ? (x > y) : (x < y)) { key[i] = y; key[ixj] = x; }
            }
        }
    __syncthreads();
    if (tid < NO) {
        int o = tid;
        int oa = (int)(key[o] & 2047ull);
        int base = (st * NO + o) * 3;
        for (int k = 0; k < 3; ++k) {
            out[OFF_OTH_TYPE + base + k] = (float)agent_type[(s * NA + oa) * 3 + k];
            out[OFF_OTH_ROLE + base + k] = (float)agent_role[(s * NA + oa) * 3 + k];
            out[OFF_OTH_SIZE + base + k] = agent_size[(s * NA + oa) * 3 + k];
        }
    }
    for (int i = tid; i < NO * NH; i += blockDim.x) {
        int o = i / NH, h = i % NH;
        unsigned long long kk = key[o];
        int oa = (int)(kk & 2047ull);
        bool dok = key_lt(kk, 2000.0);
        int gi = (s * NSTEP + h) * NA + oa;
        int hi = (st * NO + o) * NH + h;
        float2 p = *(const float2*)&agent_pos[gi * 2];
        float px = p.x - rx, py = p.y - ry;
        *(float2*)&out[OFF_OTH_POS + hi * 2] = make_float2(px * c + py * sn, -px * sn + py * c);
        float2 v = *(const float2*)&agent_vel[gi * 2];
        *(float2*)&out[OFF_OTH_VEL + hi * 2] = make_float2(v.x * c + v.y * sn, -v.x * sn + v.y * c);
        out[OFF_OTH_SPD + hi] = agent_spd[gi];
        out[OFF_OTH_ACC + hi] = agent_acc[gi];
        float dyaw = agent_yaw[gi] - ryaw;
        out[OFF_OTH_YAW + hi] = atan2f(sinf(dyaw), cosf(dyaw));
        out[OFF_OTH_YR + hi] = agent_yr[gi];
        out[OFF_OTH_VALID + hi] = (agent_valid[gi] && dok) ? 1.0f : 0.0f;
    }
}

// =====================================================================
// K4: map — per (s,t) block, 1024 threads: top-512 of 2048 by f64 dist.
// Pair-indexed bitonic (sim-verified), barrier every pass.
// =====================================================================
__global__ void __launch_bounds__(1024)
k4_map(const int* __restrict__ map_valid,
       const int* __restrict__ map_type,
       const float* __restrict__ map_pos,
       const float* __restrict__ map_dir,
       float* __restrict__ out,
       const float* __restrict__ refx_ws,
       const float* __restrict__ refy_ws,
       const float* __restrict__ refyaw_ws) {
    __shared__ unsigned long long key[NPL];
    int bid = blockIdx.x;
    int s = bid & (SS - 1), t = bid >> 4;   // scene-major for XCD/L2 grouping
    int st = s * NT + t;
    int tid = threadIdx.x;
    float rx = refx_ws[st], ry = refy_ws[st], ryaw = refyaw_ws[st];
    float c = cosf(ryaw), sn = sinf(ryaw);
    #pragma unroll
    for (int e = 0; e < 2; ++e) {
        int pl = 2 * tid + e;
        int v0 = map_valid[(s * NPL + pl) * NPLN + 0];
        float2 p = *(const float2*)&map_pos[((s * NPL + pl) * NPLN + 0) * 2];
        key[pl] = dist_key(p.x, p.y, rx, ry, pl, v0 != 0);
    }
    for (int k = 2; k <= NPL; k <<= 1)
        for (int j = k >> 1; j > 0; j >>= 1) {
            __syncthreads();
            int i = ((tid & ~(j - 1)) << 1) | (tid & (j - 1));
            int pp = i | j;
            bool up = ((i & k) == 0);
            unsigned long long x = key[i], y = key[pp];
            if (up ? (x > y) : (x < y)) { key[i] = y; key[pp] = x; }
        }
    __syncthreads();
    // gather+rotate: 2 consecutive nodes per item → float4 traffic
    for (int i = tid; i < NM * (NPLN / 2); i += 1024) {
        int r = i / (NPLN / 2), q = i % (NPLN / 2);
        int nd = 2 * q;
        unsigned long long kk = key[r];
        int pl = (int)(kk & 2047ull);
        bool dok = key_lt(kk, 3000.0);
        int gi = (s * NPL + pl) * NPLN + nd;     // even
        int oi = (st * NM + r) * NPLN + nd;      // even
        int2 mv = *(const int2*)&map_valid[gi];
        *(float2*)&out[OFF_M_VALID + oi] =
            make_float2((mv.x && dok) ? 1.0f : 0.0f, (mv.y && dok) ? 1.0f : 0.0f);
        float4 p = *(const float4*)&map_pos[gi * 2];
        float ax = p.x - rx, ay = p.y - ry;
        float bx = p.z - rx, by = p.w - ry;
        *(float4*)&out[OFF_M_POS + oi * 2] =
            make_float4(ax * c + ay * sn, -ax * sn + ay * c,
                        bx * c + by * sn, -bx * sn + by * c);
        float4 dd = *(const float4*)&map_dir[gi * 2];
        *(float4*)&out[OFF_M_DIR + oi * 2] =
            make_float4(dd.x * c + dd.y * sn, -dd.x * sn + dd.y * c,
                        dd.z * c + dd.w * sn, -dd.z * sn + dd.w * c);
    }
    for (int i = tid; i < NM * 11; i += 1024) {
        int r = i / 11, k = i % 11;
        int pl = (int)(key[r] & 2047ull);
        out[OFF_M_TYPE + (st * NM + r) * 11 + k] = (float)map_type[(s * NPL + pl) * 11 + k];
    }
}

// =====================================================================
// K5: traffic lights — per (s,t,h) block of 64 threads:
// classic bitonic on 64 elems by f64 dist, barrier every pass.
// =====================================================================
__global__ void k5_tl(const int* __restrict__ tl_valid,
                      const int* __restrict__ tl_state,
                      const float* __restrict__ tl_pos,
                      const float* __restrict__ tl_dir,
                      float* __restrict__ out,
                      const float* __restrict__ refx_ws,
                      const float* __restrict__ refy_ws,
                      const float* __restrict__ refyaw_ws) {
    __shared__ unsigned long long key[NTLS];
    int bid = blockIdx.x;
    int h = bid % NH;
    int t = (bid / NH) % NT;
    int s = bid / (NH * NT);
    int st = s * NT + t;
    int tid = threadIdx.x;
    float rx = refx_ws[st], ry = refy_ws[st], ryaw = refyaw_ws[st];
    float c = cosf(ryaw), sn = sinf(ryaw);
    {
        int stop = tid;
        int va = tl_valid[(s * NSTEP + h) * NTLS + stop];
        float2 p = *(const float2*)&tl_pos[((s * NSTEP + h) * NTLS + stop) * 2];
        key[stop] = dist_key(p.x, p.y, rx, ry, stop, va != 0);
    }
    for (int k = 2; k <= NTLS; k <<= 1)
        for (int j = k >> 1; j > 0; j >>= 1) {
            __syncthreads();
            int i = tid, ixj = i ^ j;
            if (ixj > i) {
                unsigned long long x = key[i], y = key[ixj];
                bool up = ((i & k) == 0);
                if (up ? (x > y) : (x < y)) { key[i] = y; key[ixj] = x; }
            }
        }
    __syncthreads();
    if (tid < NTL) {
        int r = tid;
        unsigned long long kk = key[r];
        int stop = (int)(kk & 2047ull);
        bool dok = key_lt(kk, 2000.0);
        int gi = (s * NSTEP + h) * NTLS + stop;
        int oi = (st * NH + h) * NTL + r;
        out[OFF_TL_VALID + oi] = (tl_valid[gi] && dok) ? 1.0f : 0.0f;
        for (int k = 0; k < 5; ++k)
            out[OFF_TL_STATE + oi * 5 + k] = (float)tl_state[gi * 5 + k];
        float2 p = *(const float2*)&tl_pos[gi * 2];
        float px = p.x - rx, py = p.y - ry;
        *(float2*)&out[OFF_TL_POS + oi * 2] = make_float2(px * c + py * sn, -px * sn + py * c);
        float2 dd = *(const float2*)&tl_dir[gi * 2];
        *(float2*)&out[OFF_TL_DIR + oi * 2] = make_float2(dd.x * c + dd.y * sn, -dd.x * sn + dd.y * c);
    }
}

// =====================================================================
extern "C" void kernel_launch(void* const* d_in, const int* in_sizes, int n_in,
                              void* d_out, int out_size, void* d_ws, size_t ws_size,
                              hipStream_t stream) {
    const int*   agent_valid = (const int*)d_in[0];
    const float* agent_pos   = (const float*)d_in[1];
    const float* agent_vel   = (const float*)d_in[2];
    const float* agent_spd   = (const float*)d_in[3];
    const float* agent_acc   = (const float*)d_in[4];
    const float* agent_yaw   = (const float*)d_in[5];
    const float* agent_yr    = (const float*)d_in[6];
    const int*   agent_type  = (const int*)d_in[7];
    const int*   agent_role  = (const int*)d_in[8];
    const float* agent_size  = (const float*)d_in[9];
    const int*   agent_cmd   = (const int*)d_in[10];
    const int*   map_valid   = (const int*)d_in[11];
    const int*   map_type    = (const int*)d_in[12];
    const float* map_pos     = (const float*)d_in[13];
    const float* map_dir     = (const float*)d_in[14];
    const int*   tl_valid    = (const int*)d_in[15];
    const int*   tl_state    = (const int*)d_in[16];
    const float* tl_pos      = (const float*)d_in[17];
    const float* tl_dir      = (const float*)d_in[18];
    float* out = (float*)d_out;

    int*   tidx_ws   = (int*)d_ws;
    float* refx_ws   = (float*)((char*)d_ws + 1024);
    float* refy_ws   = (float*)((char*)d_ws + 2048);
    float* refyaw_ws = (float*)((char*)d_ws + 3072);

    hipLaunchKernelGGL(k1_targets, dim3(SS), dim3(NA), 0, stream,
                       agent_valid, agent_pos, agent_yaw, agent_type, agent_role,
                       agent_size, agent_cmd, out, tidx_ws, refx_ws, refy_ws, refyaw_ws);

    int n2 = SS * NT * NSTEP;
    hipLaunchKernelGGL(k2_tgt, dim3((n2 + 255) / 256), dim3(256), 0, stream,
                       agent_valid, agent_pos, agent_vel, agent_spd, agent_acc,
                       agent_yaw, agent_yr, out, tidx_ws, refx_ws, refy_ws, refyaw_ws);

    hipLaunchKernelGGL(k3_others, dim3(SS * NT), dim3(NA), 0, stream,
                       agent_valid, agent_pos, agent_vel, agent_spd, agent_acc,
                       agent_yaw, agent_yr, agent_type, agent_role, agent_size,
                       out, tidx_ws, refx_ws, refy_ws, refyaw_ws);

    hipLaunchKernelGGL(k4_map, dim3(SS * NT), dim3(1024), 0, stream,
                       map_valid, map_type, map_pos, map_dir, out,
                       refx_ws, refy_ws, refyaw_ws);

    hipLaunchKernelGGL(k5_tl, dim3(SS * NT * NH), dim3(NTLS), 0, stream,
                       tl_valid, tl_state, tl_pos, tl_dir, out,
                       refx_ws, refy_ws, refyaw_ws);
}

// Round 13
// 188.411 us; speedup vs baseline: 1.0265x; 1.0265x over previous
//
#include <hip/hip_runtime.h>
#include <hip/hip_bf16.h>
#include <math.h>

// ---------------- problem constants ----------------
#define SS 16
#define NSTEP 91
#define NA 128
#define NPL 2048
#define NPLN 20
#define NTLS 64
#define SC 10          // STEP_CURRENT
#define NH 11          // N_HIST
#define NF 80          // N_FUT
#define NT 16          // N_TARGET
#define NO 64          // N_OTHER
#define NM 512         // N_MAP
#define NTL 40         // N_TL

// ---------------- output offsets (floats) ----------------
#define OFF_REF_POS   0
#define OFF_REF_ROT   512
#define OFF_TGT_POS   1536
#define OFF_TGT_VEL   7168
#define OFF_TGT_SPD   12800
#define OFF_TGT_ACC   15616
#define OFF_TGT_YAW   18432
#define OFF_TGT_YR    21248
#define OFF_TGT_SIZE  24064
#define OFF_GT_POS    24832
#define OFF_GT_VEL    65792
#define OFF_GT_SPD    106752
#define OFF_GT_YAW    127232
#define OFF_OTH_POS   147712
#define OFF_OTH_VEL   508160
#define OFF_OTH_SPD   868608
#define OFF_OTH_ACC   1048832
#define OFF_OTH_YAW   1229056
#define OFF_OTH_YR    1409280
#define OFF_OTH_SIZE  1589504
#define OFF_M_POS     1638656
#define OFF_M_DIR     6881536
#define OFF_TL_POS    12124416
#define OFF_TL_DIR    12349696
#define OFF_TIDX      12574976
#define OFF_REF_TYPE  12575232
#define OFF_REF_ROLE  12576000
#define OFF_TGT_VALID 12576768
#define OFF_GT_VALID  12579584
#define OFF_GT_CMD    12600064
#define OFF_OTH_VALID 12602112
#define OFF_OTH_TYPE  12782336
#define OFF_OTH_ROLE  12831488
#define OFF_M_VALID   12880640
#define OFF_M_TYPE    15502080
#define OFF_TL_VALID  16943872
#define OFF_TL_STATE  17056512
// total = 17619712

// ws layout (bytes): 0 tidx[256]i32 | 1024 refx[256]f32 | 2048 refy | 3072 refyaw
//                    4096  k3sel u16[256*64]  (32KB)
//                    36864 k4sel u16[256*512] (256KB)

// Sort key: FLOAT64 distance (matches numpy-f64 reference ranking), idx in 11 LSBs.
// [VERIFIED PASSING round 10]
__device__ __forceinline__ unsigned long long
dist_key(float px, float py, float rx, float ry, int idx, bool valid) {
    if (!valid) return 0x7FF0000000000000ull | (unsigned long long)(unsigned)idx;
    double dx = (double)px - (double)rx;
    double dy = (double)py - (double)ry;
    double d  = sqrt(__dadd_rn(__dmul_rn(dx, dx), __dmul_rn(dy, dy)));
    unsigned long long b = (unsigned long long)__double_as_longlong(d);
    return (b & ~2047ull) | (unsigned long long)(unsigned)idx;
}
__device__ __forceinline__ bool key_lt(unsigned long long kk, double thr) {
    double d = __longlong_as_double((long long)(kk & ~2047ull));
    return d < thr;
}

// =====================================================================
// K1: selection rounds (verified logic) + PARALLEL write phase.
// =====================================================================
__global__ void k1_targets(const int* __restrict__ agent_valid,
                           const float* __restrict__ agent_pos,
                           const float* __restrict__ agent_yaw,
                           const int* __restrict__ agent_type,
                           const int* __restrict__ agent_role,
                           const float* __restrict__ agent_size,
                           const int* __restrict__ agent_cmd,
                           float* __restrict__ out,
                           int* __restrict__ tidx_ws,
                           float* __restrict__ refx_ws,
                           float* __restrict__ refy_ws,
                           float* __restrict__ refyaw_ws) {
    __shared__ int wred[2];
    __shared__ int bests[NT];
    int s = blockIdx.x;
    int a = threadIdx.x;            // 0..127
    int w = agent_role[(s * NA + a) * 3 + 0] +
            agent_role[(s * NA + a) * 3 + 1] +
            agent_role[(s * NA + a) * 3 + 2] +
            agent_valid[(s * NSTEP + SC) * NA + a];
    int packed = (w << 8) | (127 - a);
    for (int p = 0; p < NT; ++p) {
        int v = packed;
        for (int d = 32; d > 0; d >>= 1) v = max(v, __shfl_xor(v, d));
        if ((threadIdx.x & 63) == 0) wred[threadIdx.x >> 6] = v;
        __syncthreads();
        int m = max(wred[0], wred[1]);
        __syncthreads();
        int best = 127 - (m & 0xFF);       // uniform across block
        if (a == best) packed = -1;        // remove from future rounds
        if (threadIdx.x == 0) bests[p] = best;
    }
    __syncthreads();
    // parallel per-target writes (identical computations, verified round 4)
    if (a < NT) {
        int p = a;
        int ag = bests[p];
        int st = s * NT + p;
        tidx_ws[st] = ag;
        out[OFF_TIDX + st] = (float)ag;
        float px = agent_pos[((s * NSTEP + SC) * NA + ag) * 2 + 0];
        float py = agent_pos[((s * NSTEP + SC) * NA + ag) * 2 + 1];
        float yaw = agent_yaw[(s * NSTEP + SC) * NA + ag];
        refx_ws[st] = px; refy_ws[st] = py; refyaw_ws[st] = yaw;
        float c = cosf(yaw), sn = sinf(yaw);
        out[OFF_REF_POS + st * 2 + 0] = px;
        out[OFF_REF_POS + st * 2 + 1] = py;
        out[OFF_REF_ROT + st * 4 + 0] = c;
        out[OFF_REF_ROT + st * 4 + 1] = -sn;
        out[OFF_REF_ROT + st * 4 + 2] = sn;
        out[OFF_REF_ROT + st * 4 + 3] = c;
        for (int k = 0; k < 3; ++k) {
            out[OFF_REF_TYPE + st * 3 + k] = (float)agent_type[(s * NA + ag) * 3 + k];
            out[OFF_REF_ROLE + st * 3 + k] = (float)agent_role[(s * NA + ag) * 3 + k];
            out[OFF_TGT_SIZE + st * 3 + k] = agent_size[(s * NA + ag) * 3 + k];
        }
        for (int k = 0; k < 8; ++k)
            out[OFF_GT_CMD + st * 8 + k] = (float)agent_cmd[(s * NA + ag) * 8 + k];
    }
}

// =====================================================================
// K2: target history + future [VERIFIED PASSING — untouched]
// =====================================================================
__global__ void k2_tgt(const int* __restrict__ agent_valid,
                       const float* __restrict__ agent_pos,
                       const float* __restrict__ agent_vel,
                       const float* __restrict__ agent_spd,
                       const float* __restrict__ agent_acc,
                       const float* __restrict__ agent_yaw,
                       const float* __restrict__ agent_yr,
                       float* __restrict__ out,
                       const int* __restrict__ tidx_ws,
                       const float* __restrict__ refx_ws,
                       const float* __restrict__ refy_ws,
                       const float* __restrict__ refyaw_ws) {
    int idx = blockIdx.x * blockDim.x + threadIdx.x;
    if (idx >= SS * NT * NSTEP) return;
    int step = idx % NSTEP;
    int t = (idx / NSTEP) % NT;
    int s = idx / (NSTEP * NT);
    int st = s * NT + t;
    int a = tidx_ws[st];
    float rx = refx_ws[st], ry = refy_ws[st], ryaw = refyaw_ws[st];
    float c = cosf(ryaw), sn = sinf(ryaw);
    int gi = (s * NSTEP + step) * NA + a;
    float2 p = *(const float2*)&agent_pos[gi * 2];
    float px = p.x - rx, py = p.y - ry;
    float2 v = *(const float2*)&agent_vel[gi * 2];
    float2 op = make_float2(px * c + py * sn, -px * sn + py * c);
    float2 ov = make_float2(v.x * c + v.y * sn, -v.x * sn + v.y * c);
    float spd = agent_spd[gi];
    float dyaw = agent_yaw[gi] - ryaw;
    float lyaw = atan2f(sinf(dyaw), cosf(dyaw));
    float vld = (float)agent_valid[gi];
    if (step < NH) {
        int hi = st * NH + step;
        *(float2*)&out[OFF_TGT_POS + hi * 2] = op;
        *(float2*)&out[OFF_TGT_VEL + hi * 2] = ov;
        out[OFF_TGT_SPD + hi] = spd;
        out[OFF_TGT_ACC + hi] = agent_acc[gi];
        out[OFF_TGT_YAW + hi] = lyaw;
        out[OFF_TGT_YR + hi] = agent_yr[gi];
        out[OFF_TGT_VALID + hi] = vld;
    } else {
        int fi = st * NF + (step - NH);
        *(float2*)&out[OFF_GT_POS + fi * 2] = op;
        *(float2*)&out[OFF_GT_VEL + fi * 2] = ov;
        out[OFF_GT_SPD + fi] = spd;
        out[OFF_GT_YAW + fi] = lyaw;
        out[OFF_GT_VALID + fi] = vld;
    }
}

// =====================================================================
// K3a: others SELECT — fill + bitonic sort (verified), emit u16 idx|dok.
// =====================================================================
__global__ void k3a_sel(const int* __restrict__ agent_valid,
                        const float* __restrict__ agent_pos,
                        unsigned short* __restrict__ sel_ws,
                        const int* __restrict__ tidx_ws,
                        const float* __restrict__ refx_ws,
                        const float* __restrict__ refy_ws) {
    __shared__ unsigned long long key[NA];
    int bid = blockIdx.x;
    int s = bid & (SS - 1), t = bid >> 4;
    int st = s * NT + t;
    int tid = threadIdx.x;
    float rx = refx_ws[st], ry = refy_ws[st];
    int tgt = tidx_ws[st];
    {
        int a = tid;
        int va = agent_valid[(s * NSTEP + SC) * NA + a];
        float2 p = *(const float2*)&agent_pos[((s * NSTEP + SC) * NA + a) * 2];
        key[a] = dist_key(p.x, p.y, rx, ry, a, va && (a != tgt));
    }
    for (int k = 2; k <= NA; k <<= 1)
        for (int j = k >> 1; j > 0; j >>= 1) {
            __syncthreads();
            int i = tid, ixj = i ^ j;
            if (ixj > i) {
                unsigned long long x = key[i], y = key[ixj];
                bool up = ((i & k) == 0);
                if (up ? (x > y) : (x < y)) { key[i] = y; key[ixj] = x; }
            }
        }
    __syncthreads();
    if (tid < NO) {
        unsigned long long kk = key[tid];
        sel_ws[st * NO + tid] =
            (unsigned short)((unsigned)(kk & 2047ull) | (key_lt(kk, 2000.0) ? 0x8000u : 0u));
    }
}

// =====================================================================
// K3b: others GATHER — 4 blocks per (s,t), 256 threads, streaming.
// =====================================================================
__global__ void k3b_gather(const int* __restrict__ agent_valid,
                           const float* __restrict__ agent_pos,
                           const float* __restrict__ agent_vel,
                           const float* __restrict__ agent_spd,
                           const float* __restrict__ agent_acc,
                           const float* __restrict__ agent_yaw,
                           const float* __restrict__ agent_yr,
                           const int* __restrict__ agent_type,
                           const int* __restrict__ agent_role,
                           const float* __restrict__ agent_size,
                           float* __restrict__ out,
                           const unsigned short* __restrict__ sel_ws,
                           const float* __restrict__ refx_ws,
                           const float* __restrict__ refy_ws,
                           const float* __restrict__ refyaw_ws) {
    __shared__ unsigned short sel[NO];
    int bid = blockIdx.x;
    int idx4 = bid >> 2, quarter = bid & 3;
    int s = idx4 & (SS - 1), t = idx4 >> 4;   // scene-major
    int st = s * NT + t;
    int tid = threadIdx.x;
    if (tid < NO) sel[tid] = sel_ws[st * NO + tid];
    __syncthreads();
    float rx = refx_ws[st], ry = refy_ws[st], ryaw = refyaw_ws[st];
    float c = cosf(ryaw), sn = sinf(ryaw);
    if (tid < 176) {                               // 176*4 = 704 = NO*NH
        int item = quarter * 176 + tid;
        int o = item / NH, h = item % NH;
        unsigned short sv = sel[o];
        int oa = sv & 2047;
        bool dok = (sv & 0x8000u) != 0;
        int gi = (s * NSTEP + h) * NA + oa;
        int hi = (st * NO + o) * NH + h;
        float2 p = *(const float2*)&agent_pos[gi * 2];
        float px = p.x - rx, py = p.y - ry;
        *(float2*)&out[OFF_OTH_POS + hi * 2] = make_float2(px * c + py * sn, -px * sn + py * c);
        float2 v = *(const float2*)&agent_vel[gi * 2];
        *(float2*)&out[OFF_OTH_VEL + hi * 2] = make_float2(v.x * c + v.y * sn, -v.x * sn + v.y * c);
        out[OFF_OTH_SPD + hi] = agent_spd[gi];
        out[OFF_OTH_ACC + hi] = agent_acc[gi];
        float dyaw = agent_yaw[gi] - ryaw;
        out[OFF_OTH_YAW + hi] = atan2f(sinf(dyaw), cosf(dyaw));
        out[OFF_OTH_YR + hi] = agent_yr[gi];
        out[OFF_OTH_VALID + hi] = (agent_valid[gi] && dok) ? 1.0f : 0.0f;
    }
    if (quarter == 0 && tid >= 192 && tid < 192 + NO) {   // per-other singletons
        int o = tid - 192;
        int oa = sel[o] & 2047;
        int base = (st * NO + o) * 3;
        for (int k = 0; k < 3; ++k) {
            out[OFF_OTH_TYPE + base + k] = (float)agent_type[(s * NA + oa) * 3 + k];
            out[OFF_OTH_ROLE + base + k] = (float)agent_role[(s * NA + oa) * 3 + k];
            out[OFF_OTH_SIZE + base + k] = agent_size[(s * NA + oa) * 3 + k];
        }
    }
}

// =====================================================================
// K4a: map SELECT — fill + pair-indexed bitonic (verified), emit u16.
// =====================================================================
__global__ void __launch_bounds__(1024)
k4a_sel(const int* __restrict__ map_valid,
        const float* __restrict__ map_pos,
        unsigned short* __restrict__ sel_ws,
        const float* __restrict__ refx_ws,
        const float* __restrict__ refy_ws) {
    __shared__ unsigned long long key[NPL];
    int bid = blockIdx.x;
    int s = bid & (SS - 1), t = bid >> 4;
    int st = s * NT + t;
    int tid = threadIdx.x;
    float rx = refx_ws[st], ry = refy_ws[st];
    #pragma unroll
    for (int e = 0; e < 2; ++e) {
        int pl = 2 * tid + e;
        int v0 = map_valid[(s * NPL + pl) * NPLN + 0];
        float2 p = *(const float2*)&map_pos[((s * NPL + pl) * NPLN + 0) * 2];
        key[pl] = dist_key(p.x, p.y, rx, ry, pl, v0 != 0);
    }
    for (int k = 2; k <= NPL; k <<= 1)
        for (int j = k >> 1; j > 0; j >>= 1) {
            __syncthreads();
            int i = ((tid & ~(j - 1)) << 1) | (tid & (j - 1));
            int pp = i | j;
            bool up = ((i & k) == 0);
            unsigned long long x = key[i], y = key[pp];
            if (up ? (x > y) : (x < y)) { key[i] = y; key[pp] = x; }
        }
    __syncthreads();
    if (tid < NM) {
        unsigned long long kk = key[tid];
        sel_ws[st * NM + tid] =
            (unsigned short)((unsigned)(kk & 2047ull) | (key_lt(kk, 3000.0) ? 0x8000u : 0u));
    }
}

// =====================================================================
// K4b: map GATHER — 8 blocks per (s,t), 256 threads, pure streaming.
// float4 ld/st path identical to the verified round-10 gather.
// =====================================================================
__global__ void k4b_gather(const int* __restrict__ map_valid,
                           const int* __restrict__ map_type,
                           const float* __restrict__ map_pos,
                           const float* __restrict__ map_dir,
                           float* __restrict__ out,
                           const unsigned short* __restrict__ sel_ws,
                           const float* __restrict__ refx_ws,
                           const float* __restrict__ refy_ws,
                           const float* __restrict__ refyaw_ws) {
    __shared__ unsigned short sel[NM];
    int bid = blockIdx.x;
    int idx8 = bid >> 3, oct = bid & 7;
    int s = idx8 & (SS - 1), t = idx8 >> 4;   // scene-major
    int st = s * NT + t;
    int tid = threadIdx.x;
    sel[tid] = sel_ws[st * NM + tid];
    sel[tid + 256] = sel_ws[st * NM + tid + 256];
    __syncthreads();
    float rx = refx_ws[st], ry = refy_ws[st], ryaw = refyaw_ws[st];
    float c = cosf(ryaw), sn = sinf(ryaw);
    // pairs: NM*(NPLN/2)=5120 items/st → 640 per oct
    for (int ii = tid; ii < 640; ii += 256) {
        int item = oct * 640 + ii;
        int r = item / (NPLN / 2), q = item % (NPLN / 2);
        int nd = 2 * q;
        unsigned short sv = sel[r];
        int pl = sv & 2047;
        bool dok = (sv & 0x8000u) != 0;
        int gi = (s * NPL + pl) * NPLN + nd;
        int oi = (st * NM + r) * NPLN + nd;
        int2 mv = *(const int2*)&map_valid[gi];
        *(float2*)&out[OFF_M_VALID + oi] =
            make_float2((mv.x && dok) ? 1.0f : 0.0f, (mv.y && dok) ? 1.0f : 0.0f);
        float4 p = *(const float4*)&map_pos[gi * 2];
        float ax = p.x - rx, ay = p.y - ry;
        float bx = p.z - rx, by = p.w - ry;
        *(float4*)&out[OFF_M_POS + oi * 2] =
            make_float4(ax * c + ay * sn, -ax * sn + ay * c,
                        bx * c + by * sn, -bx * sn + by * c);
        float4 dd = *(const float4*)&map_dir[gi * 2];
        *(float4*)&out[OFF_M_DIR + oi * 2] =
            make_float4(dd.x * c + dd.y * sn, -dd.x * sn + dd.y * c,
                        dd.z * c + dd.w * sn, -dd.z * sn + dd.w * c);
    }
    // types: NM*11=5632 items/st → 704 per oct
    for (int ii = tid; ii < 704; ii += 256) {
        int item = oct * 704 + ii;
        int r = item / 11, k = item % 11;
        int pl = sel[r] & 2047;
        out[OFF_M_TYPE + (st * NM + r) * 11 + k] = (float)map_type[(s * NPL + pl) * 11 + k];
    }
}

// =====================================================================
// K5: traffic lights [VERIFIED PASSING — untouched]
// =====================================================================
__global__ void k5_tl(const int* __restrict__ tl_valid,
                      const int* __restrict__ tl_state,
                      const float* __restrict__ tl_pos,
                      const float* __restrict__ tl_dir,
                      float* __restrict__ out,
                      const float* __restrict__ refx_ws,
                      const float* __restrict__ refy_ws,
                      const float* __restrict__ refyaw_ws) {
    __shared__ unsigned long long key[NTLS];
    int bid = blockIdx.x;
    int h = bid % NH;
    int t = (bid / NH) % NT;
    int s = bid / (NH * NT);
    int st = s * NT + t;
    int tid = threadIdx.x;
    float rx = refx_ws[st], ry = refy_ws[st], ryaw = refyaw_ws[st];
    float c = cosf(ryaw), sn = sinf(ryaw);
    {
        int stop = tid;
        int va = tl_valid[(s * NSTEP + h) * NTLS + stop];
        float2 p = *(const float2*)&tl_pos[((s * NSTEP + h) * NTLS + stop) * 2];
        key[stop] = dist_key(p.x, p.y, rx, ry, stop, va != 0);
    }
    for (int k = 2; k <= NTLS; k <<= 1)
        for (int j = k >> 1; j > 0; j >>= 1) {
            __syncthreads();
            int i = tid, ixj = i ^ j;
            if (ixj > i) {
                unsigned long long x = key[i], y = key[ixj];
                bool up = ((i & k) == 0);
                if (up ? (x > y) : (x < y)) { key[i] = y; key[ixj] = x; }
            }
        }
    __syncthreads();
    if (tid < NTL) {
        int r = tid;
        unsigned long long kk = key[r];
        int stop = (int)(kk & 2047ull);
        bool dok = key_lt(kk, 2000.0);
        int gi = (s * NSTEP + h) * NTLS + stop;
        int oi = (st * NH + h) * NTL + r;
        out[OFF_TL_VALID + oi] = (tl_valid[gi] && dok) ? 1.0f : 0.0f;
        for (int k = 0; k < 5; ++k)
            out[OFF_TL_STATE + oi * 5 + k] = (float)tl_state[gi * 5 + k];
        float2 p = *(const float2*)&tl_pos[gi * 2];
        float px = p.x - rx, py = p.y - ry;
        *(float2*)&out[OFF_TL_POS + oi * 2] = make_float2(px * c + py * sn, -px * sn + py * c);
        float2 dd = *(const float2*)&tl_dir[gi * 2];
        *(float2*)&out[OFF_TL_DIR + oi * 2] = make_float2(dd.x * c + dd.y * sn, -dd.x * sn + dd.y * c);
    }
}

// =====================================================================
extern "C" void kernel_launch(void* const* d_in, const int* in_sizes, int n_in,
                              void* d_out, int out_size, void* d_ws, size_t ws_size,
                              hipStream_t stream) {
    const int*   agent_valid = (const int*)d_in[0];
    const float* agent_pos   = (const float*)d_in[1];
    const float* agent_vel   = (const float*)d_in[2];
    const float* agent_spd   = (const float*)d_in[3];
    const float* agent_acc   = (const float*)d_in[4];
    const float* agent_yaw   = (const float*)d_in[5];
    const float* agent_yr    = (const float*)d_in[6];
    const int*   agent_type  = (const int*)d_in[7];
    const int*   agent_role  = (const int*)d_in[8];
    const float* agent_size  = (const float*)d_in[9];
    const int*   agent_cmd   = (const int*)d_in[10];
    const int*   map_valid   = (const int*)d_in[11];
    const int*   map_type    = (const int*)d_in[12];
    const float* map_pos     = (const float*)d_in[13];
    const float* map_dir     = (const float*)d_in[14];
    const int*   tl_valid    = (const int*)d_in[15];
    const int*   tl_state    = (const int*)d_in[16];
    const float* tl_pos      = (const float*)d_in[17];
    const float* tl_dir      = (const float*)d_in[18];
    float* out = (float*)d_out;

    int*   tidx_ws   = (int*)d_ws;
    float* refx_ws   = (float*)((char*)d_ws + 1024);
    float* refy_ws   = (float*)((char*)d_ws + 2048);
    float* refyaw_ws = (float*)((char*)d_ws + 3072);
    unsigned short* k3sel = (unsigned short*)((char*)d_ws + 4096);    // 32KB
    unsigned short* k4sel = (unsigned short*)((char*)d_ws + 36864);   // 256KB

    hipLaunchKernelGGL(k1_targets, dim3(SS), dim3(NA), 0, stream,
                       agent_valid, agent_pos, agent_yaw, agent_type, agent_role,
                       agent_size, agent_cmd, out, tidx_ws, refx_ws, refy_ws, refyaw_ws);

    hipLaunchKernelGGL(k4a_sel, dim3(SS * NT), dim3(1024), 0, stream,
                       map_valid, map_pos, k4sel, refx_ws, refy_ws);

    hipLaunchKernelGGL(k3a_sel, dim3(SS * NT), dim3(NA), 0, stream,
                       agent_valid, agent_pos, k3sel, tidx_ws, refx_ws, refy_ws);

    int n2 = SS * NT * NSTEP;
    hipLaunchKernelGGL(k2_tgt, dim3((n2 + 255) / 256), dim3(256), 0, stream,
                       agent_valid, agent_pos, agent_vel, agent_spd, agent_acc,
                       agent_yaw, agent_yr, out, tidx_ws, refx_ws, refy_ws, refyaw_ws);

    hipLaunchKernelGGL(k4b_gather, dim3(SS * NT * 8), dim3(256), 0, stream,
                       map_valid, map_type, map_pos, map_dir, out,
                       k4sel, refx_ws, refy_ws, refyaw_ws);

    hipLaunchKernelGGL(k3b_gather, dim3(SS * NT * 4), dim3(256), 0, stream,
                       agent_valid, agent_pos, agent_vel, agent_spd, agent_acc,
                       agent_yaw, agent_yr, agent_type, agent_role, agent_size,
                       out, k3sel, refx_ws, refy_ws, refyaw_ws);

    hipLaunchKernelGGL(k5_tl, dim3(SS * NT * NH), dim3(NTLS), 0, stream,
                       tl_valid, tl_state, tl_pos, tl_dir, out,
                       refx_ws, refy_ws, refyaw_ws);
}